// Round 12
// baseline (224.646 us; speedup 1.0000x reference)
//
#include <hip/hip_runtime.h>

// CTC loss forward, B=256 T=2000 L=100 C=36 (S=201, blank=35).
// FP64 linear-domain alpha recursion, one wave per batch, 4 states per lane.
// Round-12: the T3/T4 pattern done right. Cross-round diagnosis: every prior
// round exposed ~one L3 load latency (~250cy) per step -- R4/R11 compiler
// sank the loads (VGPR=32/52 prove it), R5 capped depth at 5, R7 fenced LDS
// every body with a "memory"-clobber waitcnt. Fix uses only structures the
// compiler can't defeat:
//   * global_load_lds staging (side-effecting builtin: CANNOT be sunk; zero
//     VGPR cost), 32-slot LDS ring, prefetch distance 24 rows
//   * per-body s_waitcnt vmcnt(20) with NO clobbers (no LDS fencing) +
//     sched_barrier(0) as the rule-18 fence pinning the ds_reads after it
//   * ds_read row t+4 at body t, exp'd at t+3, consumed at t+4 (~200cy slack,
//     compiler inserts its own COUNTED lgkmcnt -- never a drain)
//   * all ring indices compile-time static (32-body unrolled blocks)
//   * neighbor exchange via DPP wave_shr:1; renorm every 32 steps via DPP
//     int-max on f64 hi-words + exact pow2 exponent strip
// Per-frame softmax normalizer factors out; S_Z computed in f32 prologue.

#define BB    256
#define TT    2000
#define LLAB  100
#define CC    36
#define BLANK 35
#define LN2   0.6931471805599453

typedef __attribute__((address_space(1))) const unsigned int* as1_u32p;
typedef __attribute__((address_space(3))) unsigned int* as3_u32p;

__device__ __forceinline__ void async_row_load(const float* g, float* lds) {
  __builtin_amdgcn_global_load_lds((as1_u32p)(const void*)g,
                                   (as3_u32p)(void*)lds, 4, 0, 0);
}

// counted vmcnt wait -- NO clobbers: does not fence LDS reads (that was the
// R5/R7 mistake); ordering of the following ds_reads is provided by SB0.
#define WAITV(n) asm volatile("s_waitcnt vmcnt(" #n ")")
#define SB0 __builtin_amdgcn_sched_barrier(0)

static __device__ __forceinline__ int imax(int a, int b) { return a > b ? a : b; }

// lane i gets lane i-1's value; lane 0 gets 0.  (DPP wave_shr:1, zero-fill)
static __device__ __forceinline__ double dpp_up1(double x) {
  long long v = __double_as_longlong(x);
  int lo = (int)(unsigned int)(v & 0xFFFFFFFFLL);
  int hi = (int)(v >> 32);
  int slo = __builtin_amdgcn_update_dpp(0, lo, 0x138, 0xF, 0xF, true);
  int shi = __builtin_amdgcn_update_dpp(0, hi, 0x138, 0xF, 0xF, true);
  long long r = ((long long)shi << 32) | (long long)(unsigned int)slo;
  return __longlong_as_double(r);
}

// wave-wide int max via DPP, broadcast from lane 63.
static __device__ __forceinline__ int wave_imax(int x) {
  x = imax(x, __builtin_amdgcn_update_dpp(x, x, 0x111, 0xF, 0xF, false));
  x = imax(x, __builtin_amdgcn_update_dpp(x, x, 0x112, 0xF, 0xF, false));
  x = imax(x, __builtin_amdgcn_update_dpp(x, x, 0x114, 0xF, 0xF, false));
  x = imax(x, __builtin_amdgcn_update_dpp(x, x, 0x118, 0xF, 0xF, false));
  x = imax(x, __builtin_amdgcn_update_dpp(x, x, 0x142, 0xA, 0xF, false));
  x = imax(x, __builtin_amdgcn_update_dpp(x, x, 0x143, 0xC, 0xF, false));
  return __builtin_amdgcn_readlane(x, 63);
}

__global__ __launch_bounds__(64) void ctc_fused(
    const float* __restrict__ logits,
    const int*   __restrict__ input_labels,
    const int*   __restrict__ input_len,
    const int*   __restrict__ label_len,
    float*       __restrict__ out)
{
  __shared__ float ring[33][CC];     // 32 slots + sink (slot 32); 4752 B
  const int b    = blockIdx.x;
  const int lane = threadIdx.x;
  const float* lg = logits + (size_t)b * TT * CC;
  const int ilen = input_len[b];
  const int llen = label_len[b];

  // ---------------- prologue: S_Z = sum of per-frame logsumexp ------------
  float sz = 0.f;
  for (int t = lane; t < TT; t += 64) {
    const float4* r4 = (const float4*)(lg + t * CC);   // 144B row, 16B aligned
    float4 q[9];
#pragma unroll
    for (int i = 0; i < 9; ++i) q[i] = r4[i];
    float m = q[0].x;
#pragma unroll
    for (int i = 0; i < 9; ++i) {
      m = fmaxf(m, q[i].x); m = fmaxf(m, q[i].y);
      m = fmaxf(m, q[i].z); m = fmaxf(m, q[i].w);
    }
    float s = 0.f;
#pragma unroll
    for (int i = 0; i < 9; ++i) {
      s += __expf(q[i].x - m) + __expf(q[i].y - m)
         + __expf(q[i].z - m) + __expf(q[i].w - m);
    }
    float z = m + __logf(s);
    if (t == 0 || t < ilen) sz += z;
  }
#pragma unroll
  for (int o = 32; o; o >>= 1) sz += __shfl_xor(sz, o, 64);
  const float S_Z = sz;

  // ---------------- per-lane static state (states 4l..4l+3) ---------------
  const int* lb = input_labels + b * LLAB;
  const int i0 = 2 * lane, i1 = 2 * lane + 1, im = 2 * lane - 1;
  const int c1 = (i0 < LLAB) ? lb[i0] : 0;            // ext[4l+1]
  const int c3 = (i1 < LLAB) ? lb[i1] : 0;            // ext[4l+3]
  const int cm = (im >= 0 && im < LLAB) ? lb[im] : 0;
  const bool skip1 = (lane >= 1) && (c1 != BLANK) && (c1 != cm);
  const bool skip3 = (c3 != BLANK) && (c3 != c1);
  const int cb = BLANK, cc1 = c1, cc3 = c3;           // column indices

  // ---------------- t=0 init ----------------------------------------------
  double a0 = 0.0, a1 = 0.0, a2 = 0.0, a3 = 0.0;
  {
    float eb = lg[BLANK];
    float e1 = lg[c1];
    if (lane == 0) { a0 = (double)__expf(eb); a1 = (double)__expf(e1); }
  }

  // drain everything; from here vmcnt counts ONLY ring loads
  asm volatile("s_waitcnt vmcnt(0) lgkmcnt(0)" ::: "memory");

  // pre-issue rows 1..24 -> slots 1..24  (24 outstanding)
#pragma unroll
  for (int r = 1; r <= 24; ++r) {
    if (lane < CC) async_row_load(lg + (size_t)r * CC + lane, &ring[r & 31][0]);
  }

  // preamble: rows 1..4 resident; pv for frame 1; reg slots for rows 2,3,4
  float fb[4], f1[4], f3[4];
  double pv0, pv1, pv3;
  WAITV(20);                        // retired >= 4 -> rows 1..4 in LDS
  SB0;
  pv0 = (double)__expf(ring[1][cb]);
  pv1 = (double)__expf(ring[1][cc1]);
  pv3 = (double)__expf(ring[1][cc3]);
  fb[2] = ring[2][cb]; f1[2] = ring[2][cc1]; f3[2] = ring[2][cc3]; // row 2
  fb[3] = ring[3][cb]; f1[3] = ring[3][cc1]; f3[3] = ring[3][cc3]; // row 3
  fb[0] = ring[4][cb]; f1[0] = ring[4][cc1]; f3[0] = ring[4][cc3]; // row 4

  double n3 = 0.0, n3k = 0.0;       // prev-lane a3 (and skip1-gated copy)
  int Eacc = 0;                     // sum of stripped power-of-2 exponents
  const float* pf = lg + (size_t)25 * CC;     // next row base to prefetch
  const float* lgLast = lg + (size_t)(TT - 1) * CC;

  // body for step t = tb + J (tb % 32 == 1, so all &31/&3 slots are static):
  //   issue row t+24 -> slot (J+25)&31         [gload_lds: un-sinkable]
  //   WAITV(20): retired >= t+4 -> rows <= t+4 in LDS
  //   SB0: pin the following ds_reads after the waitcnt
  //   ds_read row t+4 -> reg slot (J+5)&3      [exp'd at t+3, used at t+4]
  //   exp reg slot (J+2)&3 (= row t+1) -> pv for next body
  //   alpha update with pv_t; n3 = dpp(a3)
#define STEP(J, T, SRC, DST)                                               \
  {                                                                        \
    if (lane < CC) async_row_load((SRC) + lane, DST);                      \
    pf += CC;                                                              \
    WAITV(20);                                                             \
    SB0;                                                                   \
    const float* rp_ = &ring[((J) + 5) & 31][0];                           \
    fb[((J) + 5) & 3] = rp_[cb];                                           \
    f1[((J) + 5) & 3] = rp_[cc1];                                          \
    f3[((J) + 5) & 3] = rp_[cc3];                                          \
    double q0 = (double)__expf(fb[((J) + 2) & 3]);                         \
    double q1 = (double)__expf(f1[((J) + 2) & 3]);                         \
    double q3 = (double)__expf(f3[((J) + 2) & 3]);                         \
    if ((T) < ilen) {                                                      \
      double g3 = skip3 ? a1 : 0.0;                                        \
      double u0 = (a0 + n3) * pv0;                                         \
      double u1 = (a1 + a0 + n3k) * pv1;                                   \
      double u2 = (a2 + a1) * pv0;        /* pv2 == pv0 (blank) */         \
      double u3 = (a3 + a2 + g3) * pv3;                                    \
      a0 = u0; a1 = u1; a2 = u2; a3 = u3;                                  \
    }                                                                      \
    n3  = dpp_up1(a3);                                                     \
    n3k = skip1 ? n3 : 0.0;                                                \
    pv0 = q0; pv1 = q1; pv3 = q3;                                          \
  }

#define RENORM                                                             \
  {                                                                        \
    int h0 = (int)(__double_as_longlong(a0) >> 32);                        \
    int h1 = (int)(__double_as_longlong(a1) >> 32);                        \
    int h2 = (int)(__double_as_longlong(a2) >> 32);                        \
    int h3 = (int)(__double_as_longlong(a3) >> 32);                        \
    int ebias = wave_imax(imax(imax(h0, h1), imax(h2, h3))) >> 20;         \
    Eacc += ebias - 1023;                                                  \
    double scale = __longlong_as_double((long long)(2046 - ebias) << 52);  \
    a0 *= scale; a1 *= scale; a2 *= scale; a3 *= scale;                    \
    n3 *= scale; n3k *= scale;                                             \
  }

  // main loop: 61 blocks of 32 bodies, t = 1..1952 (issues rows 25..1976)
#pragma unroll 1
  for (int tb = 1; tb <= 1921; tb += 32) {
#pragma unroll
    for (int j = 0; j < 32; ++j) {
      const int t = tb + j;
      STEP(j, t, pf, &ring[(j + 25) & 31][0])
    }
    RENORM
  }
  // guarded blocks: literal tb so the clamp folds at compile time.
  // tb=1953: bodies 1953..1984, issues rows 1977..2008 (clamp >=2000)
  // tb=1985: bodies 1985..2016, issues all clamped; updates stop at ilen.
  {
#pragma unroll
    for (int j = 0; j < 32; ++j) {
      const int t = 1953 + j;
      const float* src = (t + 24 < TT) ? pf : lgLast;
      float* dst = (t + 24 < TT) ? &ring[(j + 25) & 31][0] : &ring[32][0];
      STEP(j, t, src, dst)
    }
    RENORM
  }
  {
#pragma unroll
    for (int j = 0; j < 32; ++j) {
      const int t = 1985 + j;
      STEP(j, t, lgLast, &ring[32][0])
    }
    RENORM
  }

  // drain outstanding ring loads before workgroup teardown
  asm volatile("s_waitcnt vmcnt(0)" ::: "memory");

  // ---------------- finalize ----------------------------------------------
  const int sb  = 4 * lane;
  const int end = 2 * llen;
  const int ep  = (end > 0) ? (end - 1) : 0;
  double contrib = 0.0;
  contrib += ((sb + 0 == end) ? a0 : 0.0) + ((sb + 0 == ep) ? a0 : 0.0);
  contrib += ((sb + 1 == end) ? a1 : 0.0) + ((sb + 1 == ep) ? a1 : 0.0);
  contrib += ((sb + 2 == end) ? a2 : 0.0) + ((sb + 2 == ep) ? a2 : 0.0);
  contrib += ((sb + 3 == end) ? a3 : 0.0) + ((sb + 3 == ep) ? a3 : 0.0);
#pragma unroll
  for (int o = 32; o; o >>= 1) contrib += __shfl_xor(contrib, o, 64);

  if (lane == 0) {
    long long u = __double_as_longlong(contrib);
    int e = (int)((u >> 52) & 0x7FF) - 1023;
    double mant = __longlong_as_double(
        (u & 0xFFFFFFFFFFFFFULL) | 0x3FF0000000000000ULL);
    double lc = (double)e * LN2 + (double)__logf((float)mant);
    double loss = -(lc + (double)Eacc * LN2 - (double)S_Z);
    out[b] = (float)loss;
  }
#undef STEP
#undef RENORM
}

extern "C" void kernel_launch(void* const* d_in, const int* in_sizes, int n_in,
                              void* d_out, int out_size, void* d_ws, size_t ws_size,
                              hipStream_t stream) {
  const float* logits = (const float*)d_in[0];
  const int* labels   = (const int*)d_in[1];
  const int* ilen     = (const int*)d_in[2];
  const int* llen     = (const int*)d_in[3];
  float* out          = (float*)d_out;
  (void)in_sizes; (void)n_in; (void)out_size; (void)d_ws; (void)ws_size;
  hipLaunchKernelGGL(ctc_fused, dim3(BB), dim3(64), 0, stream,
                     logits, labels, ilen, llen, out);
}